// Round 4
// baseline (1516.430 us; speedup 1.0000x reference)
//
#include <hip/hip_runtime.h>
#include <math.h>

// EmergentResonator — R7: deeper B-cache + input-MFMA lookahead.
// R6 (736us): caching 4/12 kt of B (regs+LDS) cut streamed bytes 31% -> -5%.
// Model: per CU-step ~6.7k cyc of L2/L1 B-stream service + ~1.2k MFMA + 2-3k
// VALU tail inside a 22k-cycle step at fixed 2 waves/SIMD; stream & serial
// path both matter. R7:
//  - B cache: kt0-3 in regs (96 VGPR; budget 256), kt4-5 + bh(kt6) in LDS
//    (120KB). Streamed: bl(kt6)+kt7-11 = 264KB/step (was 384KB).
//  - Input lookahead: gated-input contribution for t+1 depends only on
//    x(t+1); compute it at END of step t into next_in[3][4] regs. Its Wio L2
//    loads + 18 MFMAs overlap barrier slack; step t's serial GEMM->LN path
//    loses the whole input phase. FP order identical (added after recurrent
//    sum, same spot) -> absmax must stay 0.0078.
//  - x staging: per-thread (m,f) hoisted (no div/mod in loop).
// Sentinels: WRITE_SIZE ~160KB (spill alarm -> revert reg cache to 3 kt);
// absmax == 0.0078; LDS 149KB.

#define NET    360
#define NPAD   384
#define K8N    48          // NPAD/8 k8-groups for W_rec
#define RPB    16
#define NBLK   256
#define NTHR   512         // 8 waves; wave w owns n-tiles 3w..3w+2
#define NTILE  3

typedef _Float16 f16x8 __attribute__((ext_vector_type(8)));
typedef float    f32x4 __attribute__((ext_vector_type(4)));

#define WREC_E (K8N * NPAD * 8)    // 147456 f16 per term
#define WIN_E  (4 * NPAD * 8)      // 12288 f16 per term (K pad 32)

// Split fp32 weights into f16 hi/lo in MFMA B-fragment layout:
// idx = (k8*NPAD + n)*8 + (k&7), B[k][n] = W[n*K + k], zero-padded.
__global__ void prep_kernel(const float* __restrict__ W_rec,
                            const float* __restrict__ W_in,
                            const float* __restrict__ W_gate,
                            _Float16* __restrict__ Bh, _Float16* __restrict__ Bl,
                            _Float16* __restrict__ Wio)
{
    int idx = blockIdx.x * 256 + threadIdx.x;
    if (idx < WREC_E) {
        int k8 = idx / (NPAD * 8), rem = idx % (NPAD * 8);
        int n = rem >> 3, j = rem & 7, k = k8 * 8 + j;
        float v = (k < NET && n < NET) ? W_rec[n * NET + k] : 0.f;
        _Float16 h = (_Float16)v;
        Bh[idx] = h; Bl[idx] = (_Float16)(v - (float)h);
    } else if (idx < WREC_E + 2 * WIN_E) {
        // Wio layout: [0]=Wih, [1]=Wil, [2]=Wgh, [3]=Wgl, each WIN_E f16.
        int e = idx - WREC_E;                 // 0 .. 2*WIN_E-1
        int which = e / WIN_E;                // 0 = W_in, 1 = W_gate
        int f = e % WIN_E;
        int k8 = f / (NPAD * 8), rem = f % (NPAD * 8);
        int n = rem >> 3, j = rem & 7, k = k8 * 8 + j;
        const float* W = which ? W_gate : W_in;
        float v = (k < 28 && n < NET) ? W[n * 28 + k] : 0.f;
        _Float16 h = (_Float16)v;
        Wio[(2 * which) * WIN_E + f]     = h;
        Wio[(2 * which + 1) * WIN_E + f] = (_Float16)(v - (float)h);
    }
}

__device__ __forceinline__ float sigm(float v) { return 1.f / (1.f + __expf(-v)); }

__global__ __launch_bounds__(NTHR, 2)
void resonator_kernel(const float* __restrict__ x,
                      const int*   __restrict__ rsteps_p,
                      const float* __restrict__ b_in,
                      const float* __restrict__ b_gate,
                      const float* __restrict__ ln_g,
                      const float* __restrict__ ln_b,
                      const float* __restrict__ thr_p,
                      const float* __restrict__ intr_p,
                      const float* __restrict__ steep_p,
                      const float* __restrict__ reset_p,
                      const float* __restrict__ W_cls,
                      const float* __restrict__ b_cls,
                      const _Float16* __restrict__ Bh_g,
                      const _Float16* __restrict__ Bl_g,
                      const _Float16* __restrict__ Wio_g,
                      float* __restrict__ out)
{
    // Spikes in A-fragment layout, f16 hi/lo: idx = (k8*16 + m)*8 + (k&7)
    __shared__ __align__(16) _Float16 Ah[K8N * RPB * 8];       // 12 KB
    __shared__ __align__(16) _Float16 Al[K8N * RPB * 8];       // 12 KB
    __shared__ __align__(16) _Float16 xbuf[2][2][4 * RPB * 8]; // 4 KB [par][h/l]
    __shared__ __align__(16) _Float16 BcA[8 * 12 * 64 * 8];    // 96 KB: kt4-5 h+l
    __shared__ __align__(16) _Float16 BcB[8 * 3 * 64 * 8];     // 24 KB: kt6 h only
    __shared__ float red[8][33];                               // LN partials

    const int tid  = threadIdx.x;
    const int w    = tid >> 6;
    const int lane = tid & 63;
    const int quad = lane >> 4;
    const int l15  = lane & 15;
    const int row0 = blockIdx.x * RPB;

    // Per-column params for this thread's NTILE n-values (n = (w*3+i)*16 + l15)
    float gam[NTILE], bet[NTILE], thrv[NTILE], intv[NTILE], asp[NTILE], rscv[NTILE],
          binv[NTILE], bgtv[NTILE];
#pragma unroll
    for (int i = 0; i < NTILE; ++i) {
        int n_i = (w * NTILE + i) * 16 + l15;
        bool a = n_i < NET;
        gam[i]  = a ? ln_g[n_i]   : 0.f;
        bet[i]  = a ? ln_b[n_i]   : 0.f;
        thrv[i] = a ? thr_p[n_i]  : 0.f;
        intv[i] = a ? intr_p[n_i] : 0.f;
        asp[i]  = a ? fabsf(steep_p[n_i]) : 0.f;
        rscv[i] = a ? reset_p[n_i] : 0.f;
        binv[i] = a ? b_in[n_i]   : 0.f;
        bgtv[i] = a ? b_gate[n_i] : 0.f;
    }

    float pot[NTILE][4];
#pragma unroll
    for (int i = 0; i < NTILE; ++i)
#pragma unroll
        for (int r = 0; r < 4; ++r) pot[i][r] = 0.f;

    // Zero-init spike + x LDS (x pad cols stay 0 forever).
    for (int e = tid; e < K8N * RPB * 8; e += NTHR) { Ah[e] = (_Float16)0.f; Al[e] = (_Float16)0.f; }
    for (int e = tid; e < 2 * 2 * 4 * RPB * 8; e += NTHR) ((_Float16*)xbuf)[e] = (_Float16)0.f;

    const f16x8* Bph = (const f16x8*)Bh_g;
    const f16x8* Bpl = (const f16x8*)Bl_g;
    const f16x8* Aph = (const f16x8*)Ah;
    const f16x8* Apl = (const f16x8*)Al;
    const f16x8* Wp  = (const f16x8*)Wio_g;     // input weights: global (L2-hot)
    f16x8* BcAv = (f16x8*)BcA;
    f16x8* BcBv = (f16x8*)BcB;
    const int bb = quad * NPAD + w * (NTILE * 16) + l15;  // B-frag base (f16x8 units)

    // ---- Step-invariant B cache: kt0-3 regs, kt4-5 + bh(kt6) LDS ----
    f16x8 rbh[4][NTILE], rbl[4][NTILE];
#pragma unroll
    for (int kt = 0; kt < 4; ++kt)
#pragma unroll
        for (int i = 0; i < NTILE; ++i) {
            rbh[kt][i] = Bph[bb + i * 16 + kt * (4 * NPAD)];
            rbl[kt][i] = Bpl[bb + i * 16 + kt * (4 * NPAD)];
        }
#pragma unroll
    for (int kt = 4; kt < 6; ++kt)
#pragma unroll
        for (int i = 0; i < NTILE; ++i) {
            int op = (kt - 4) * 6 + i * 2;
            BcAv[(w * 12 + op) * 64 + lane]     = Bph[bb + i * 16 + kt * (4 * NPAD)];
            BcAv[(w * 12 + op + 1) * 64 + lane] = Bpl[bb + i * 16 + kt * (4 * NPAD)];
        }
#pragma unroll
    for (int i = 0; i < NTILE; ++i)
        BcBv[(w * 3 + i) * 64 + lane] = Bph[bb + i * 16 + 6 * (4 * NPAD)];

    // x staging: each thread owns one (m,f) element, fixed for all steps.
    const bool xact = tid < RPB * 28;
    const int  xm   = tid / 28;
    const int  xf   = tid - xm * 28;
    const int  xix  = ((xf >> 3) * RPB + xm) * 8 + (xf & 7);
    const float* xsrc = x + ((size_t)(row0 + xm) * 64) * 28 + xf;

    // Stage x for t=0 into parity-0 buffer.
    if (xact) {
        float v = xsrc[0];
        _Float16 h = (_Float16)v;
        xbuf[0][0][xix] = h; xbuf[0][1][xix] = (_Float16)(v - (float)h);
    }
    __syncthreads();

    // Gated-input lookahead: next_in[i][r] = input contribution for the
    // UPCOMING step, computed from x already staged in xbuf[par].
    float next_in[NTILE][4];
#define COMPUTE_NEXT_IN(PAR)                                                      \
    {                                                                             \
        const f16x8* Xh = (const f16x8*)xbuf[(PAR)][0];                           \
        const f16x8* Xl = (const f16x8*)xbuf[(PAR)][1];                           \
        f16x8 xa = Xh[lane];                                                      \
        f16x8 xb = Xl[lane];                                                      \
        _Pragma("unroll")                                                         \
        for (int i = 0; i < NTILE; ++i) {                                         \
            f16x8 ih = Wp[0 * (WIN_E / 8) + bb + i * 16];                         \
            f16x8 il = Wp[1 * (WIN_E / 8) + bb + i * 16];                         \
            f16x8 gh = Wp[2 * (WIN_E / 8) + bb + i * 16];                         \
            f16x8 gl = Wp[3 * (WIN_E / 8) + bb + i * 16];                         \
            f32x4 ia = (f32x4){binv[i], binv[i], binv[i], binv[i]};               \
            f32x4 ga = (f32x4){bgtv[i], bgtv[i], bgtv[i], bgtv[i]};               \
            ia = __builtin_amdgcn_mfma_f32_16x16x32_f16(xa, ih, ia, 0, 0, 0);     \
            ia = __builtin_amdgcn_mfma_f32_16x16x32_f16(xb, ih, ia, 0, 0, 0);     \
            ia = __builtin_amdgcn_mfma_f32_16x16x32_f16(xa, il, ia, 0, 0, 0);     \
            ga = __builtin_amdgcn_mfma_f32_16x16x32_f16(xa, gh, ga, 0, 0, 0);     \
            ga = __builtin_amdgcn_mfma_f32_16x16x32_f16(xb, gh, ga, 0, 0, 0);     \
            ga = __builtin_amdgcn_mfma_f32_16x16x32_f16(xa, gl, ga, 0, 0, 0);     \
            _Pragma("unroll")                                                     \
            for (int r = 0; r < 4; ++r) next_in[i][r] = ia[r] * sigm(ga[r]);      \
        }                                                                         \
    }
    COMPUTE_NEXT_IN(0)   // input for t=0

    const int Ttot = 64 + *rsteps_p;

    for (int t = 0; t < Ttot; ++t) {
        __syncthreads();   // barrier A: spikes/x/caches for step t visible

        f32x4 acc[NTILE];
#pragma unroll
        for (int i = 0; i < NTILE; ++i) acc[i] = (f32x4){0.f, 0.f, 0.f, 0.f};

        // ---- kt0-3 from register cache: zero-latency opening ----
#pragma unroll
        for (int kt = 0; kt < 4; ++kt) {
            f16x8 ah = Aph[lane + kt * 64];
            f16x8 al = Apl[lane + kt * 64];
#pragma unroll
            for (int i = 0; i < NTILE; ++i) {
                acc[i] = __builtin_amdgcn_mfma_f32_16x16x32_f16(ah, rbh[kt][i], acc[i], 0, 0, 0);
                acc[i] = __builtin_amdgcn_mfma_f32_16x16x32_f16(al, rbh[kt][i], acc[i], 0, 0, 0);
                acc[i] = __builtin_amdgcn_mfma_f32_16x16x32_f16(ah, rbl[kt][i], acc[i], 0, 0, 0);
            }
        }
        // ---- kt4-5 from LDS cache ----
#pragma unroll
        for (int kt = 4; kt < 6; ++kt) {
            f16x8 ah = Aph[lane + kt * 64];
            f16x8 al = Apl[lane + kt * 64];
#pragma unroll
            for (int i = 0; i < NTILE; ++i) {
                f16x8 bh = BcAv[(w * 12 + (kt - 4) * 6 + i * 2) * 64 + lane];
                f16x8 bl = BcAv[(w * 12 + (kt - 4) * 6 + i * 2 + 1) * 64 + lane];
                acc[i] = __builtin_amdgcn_mfma_f32_16x16x32_f16(ah, bh, acc[i], 0, 0, 0);
                acc[i] = __builtin_amdgcn_mfma_f32_16x16x32_f16(al, bh, acc[i], 0, 0, 0);
                acc[i] = __builtin_amdgcn_mfma_f32_16x16x32_f16(ah, bl, acc[i], 0, 0, 0);
            }
        }
        // ---- kt6: bh from LDS, bl streamed ----
        {
            f16x8 ah = Aph[lane + 6 * 64];
            f16x8 al = Apl[lane + 6 * 64];
#pragma unroll
            for (int i = 0; i < NTILE; ++i) {
                f16x8 bh = BcBv[(w * 3 + i) * 64 + lane];
                f16x8 bl = Bpl[bb + i * 16 + 6 * (4 * NPAD)];
                acc[i] = __builtin_amdgcn_mfma_f32_16x16x32_f16(ah, bh, acc[i], 0, 0, 0);
                acc[i] = __builtin_amdgcn_mfma_f32_16x16x32_f16(al, bh, acc[i], 0, 0, 0);
                acc[i] = __builtin_amdgcn_mfma_f32_16x16x32_f16(ah, bl, acc[i], 0, 0, 0);
            }
        }
        // ---- kt7-11 streamed from L2 ----
#pragma unroll 2
        for (int q = 7; q < 12; ++q) {
            f16x8 ah = Aph[lane + q * 64];
            f16x8 al = Apl[lane + q * 64];
#pragma unroll
            for (int i = 0; i < NTILE; ++i) {
                f16x8 bh = Bph[bb + i * 16 + q * (4 * NPAD)];
                f16x8 bl = Bpl[bb + i * 16 + q * (4 * NPAD)];
                acc[i] = __builtin_amdgcn_mfma_f32_16x16x32_f16(ah, bh, acc[i], 0, 0, 0);
                acc[i] = __builtin_amdgcn_mfma_f32_16x16x32_f16(al, bh, acc[i], 0, 0, 0);
                acc[i] = __builtin_amdgcn_mfma_f32_16x16x32_f16(ah, bl, acc[i], 0, 0, 0);
            }
        }

        // ---- Add precomputed gated-input contribution (same FP position) ----
        if (t < 64) {
#pragma unroll
            for (int i = 0; i < NTILE; ++i)
#pragma unroll
                for (int r = 0; r < 4; ++r) acc[i][r] += next_in[i][r];
        }

        // ---- Stage x for t+1 into the other parity buffer ----
        if (t < 63 && xact) {
            float v = xsrc[(t + 1) * 28];
            _Float16 h = (_Float16)v;
            xbuf[(t + 1) & 1][0][xix] = h;
            xbuf[(t + 1) & 1][1][xix] = (_Float16)(v - (float)h);
        }

        // ---- LN stats stage 1: reduce over this wave's 48 columns ----
#pragma unroll
        for (int r = 0; r < 4; ++r) {
            float v  = acc[0][r] + acc[1][r] + acc[2][r];
            float v2 = acc[0][r] * acc[0][r] + acc[1][r] * acc[1][r] + acc[2][r] * acc[2][r];
#pragma unroll
            for (int off = 1; off < 16; off <<= 1) {
                v  += __shfl_xor(v,  off);
                v2 += __shfl_xor(v2, off);
            }
            if (l15 == 0) {
                red[w][(quad * 4 + r) * 2]     = v;
                red[w][(quad * 4 + r) * 2 + 1] = v2;
            }
        }

        __syncthreads();   // barrier B: red[] + x(t+1) visible

        // ---- LN finish, redundant per wave ----
        float mu_r[4], rs_r[4];
#pragma unroll
        for (int r = 0; r < 4; ++r) {
            int row2 = (quad * 4 + r) * 2;
            float val = red[l15 & 7][row2 + (l15 >> 3)];
            val += __shfl_xor(val, 1);
            val += __shfl_xor(val, 2);
            val += __shfl_xor(val, 4);
            float other = __shfl_xor(val, 8);
            float S  = (l15 < 8) ? val : other;    // sum of cur
            float S2 = (l15 < 8) ? other : val;    // sum of cur^2
            float mu = S * (1.f / NET);
            mu_r[r] = mu;
            rs_r[r] = rsqrtf(S2 * (1.f / NET) - mu * mu + 1e-5f);
        }

        // ---- LN apply + PulseTGAU neuron, write split spikes to A-layout ----
#pragma unroll
        for (int i = 0; i < NTILE; ++i) {
            int n_i  = (w * NTILE + i) * 16 + l15;
            int base = ((n_i >> 3) * RPB) * 8 + (n_i & 7);
#pragma unroll
            for (int r = 0; r < 4; ++r) {
                int m = quad * 4 + r;
                float cur = (acc[i][r] - mu_r[r]) * rs_r[r] * gam[i] + bet[i];
                float p   = pot[i][r] * 0.95f + cur + intv[i];
                float gp  = p - thrv[i];
                float sg  = sigm(gp * asp[i]);
                float sp  = sigm(gp);
                float o   = gp * sp * sg;
                pot[i][r] = p - rscv[i] * (gp * sg);
                _Float16 h = (_Float16)o;
                Ah[base + m * 8] = h;
                Al[base + m * 8] = (_Float16)(o - (float)h);
            }
        }

        // ---- Lookahead: input contribution for step t+1 (overlaps barrier) ----
        if (t < 63) COMPUTE_NEXT_IN((t + 1) & 1)
    }

    __syncthreads();
    // ---- Classifier epilogue ----
    if (tid < RPB * 10) {
        int r = tid / 10, c = tid - r * 10;
        const float* wc = W_cls + c * NET;
        float s = b_cls[c];
        for (int k = 0; k < NET; ++k) {
            int ix = ((k >> 3) * RPB + r) * 8 + (k & 7);
            float sv = (float)Ah[ix] + (float)Al[ix];
            s = fmaf(sv, wc[k], s);
        }
        out[(size_t)(row0 + r) * 10 + c] = s;
    }
}

extern "C" void kernel_launch(void* const* d_in, const int* in_sizes, int n_in,
                              void* d_out, int out_size, void* d_ws, size_t ws_size,
                              hipStream_t stream)
{
    const float* x      = (const float*)d_in[0];
    const int*   rsteps = (const int*)  d_in[1];
    const float* W_in   = (const float*)d_in[2];
    const float* b_in   = (const float*)d_in[3];
    const float* W_gate = (const float*)d_in[4];
    const float* b_gate = (const float*)d_in[5];
    const float* W_rec  = (const float*)d_in[6];
    const float* ln_g   = (const float*)d_in[7];
    const float* ln_b   = (const float*)d_in[8];
    const float* thr    = (const float*)d_in[9];
    const float* intr   = (const float*)d_in[10];
    const float* steep  = (const float*)d_in[11];
    const float* rsc    = (const float*)d_in[12];
    const float* W_cls  = (const float*)d_in[13];
    const float* b_cls  = (const float*)d_in[14];
    float*       out    = (float*)d_out;

    _Float16* Bh  = (_Float16*)d_ws;
    _Float16* Bl  = Bh + WREC_E;
    _Float16* Wio = Bl + WREC_E;     // 4*WIN_E: Wih, Wil, Wgh, Wgl

    const int total = WREC_E + 2 * WIN_E;
    prep_kernel<<<dim3((total + 255) / 256), dim3(256), 0, stream>>>(
        W_rec, W_in, W_gate, Bh, Bl, Wio);
    resonator_kernel<<<dim3(NBLK), dim3(NTHR), 0, stream>>>(
        x, rsteps, b_in, b_gate, ln_g, ln_b, thr, intr, steep, rsc,
        W_cls, b_cls, Bh, Bl, Wio, out);
}

// Round 5
// 768.729 us; speedup vs baseline: 1.9726x; 1.9726x over previous
//
#include <hip/hip_runtime.h>
#include <math.h>

// EmergentResonator — R8: R6 base + input lookahead, under the 128-reg tier.
// R7 post-mortem: allocator pins at arch-VGPR tiers {64,128} and SPILLS rather
// than relax to the 256-reg budget launch_bounds(512,2) allows (VGPR_Count
// stuck at 128, WRITE 334MB, FETCH 2.7GB). Hard rule: keep arch-VGPR demand
// <= ~126. R6 (736us, 124 regs) is the verified base.
// R8 changes vs R6 (register-neutral-minus):
//  - Reg B-cache shrinks 2kt -> 1kt (kt0 only, 24 VGPR; frees 24).
//  - LDS B-cache: kt1-2 full (96KB) + bh(kt3) (24KB). Streamed: bl(kt3) +
//    kt4-11 = 408KB/step (was 384; +6% stream is the price).
//  - Input-MFMA lookahead (+12 regs next_in): gated-input contribution for
//    t+1 computed at END of step t (depends only on x(t+1), staged before
//    barrier B). Removes 18 MFMAs + 12 L2 loads + 12 sigm from the serial
//    GEMM->LN path; FP order identical (added at same point) -> absmax 0.0078.
//  - x staging keeps R7's hoisted per-thread (m,f) (no div/mod in loop).
// Net reg estimate ~112. Sentinels: VGPR_Count <= 126, WRITE_SIZE ~160KB,
// absmax == 0.0078125.

#define NET    360
#define NPAD   384
#define K8N    48          // NPAD/8 k8-groups for W_rec
#define RPB    16
#define NBLK   256
#define NTHR   512         // 8 waves; wave w owns n-tiles 3w..3w+2
#define NTILE  3

typedef _Float16 f16x8 __attribute__((ext_vector_type(8)));
typedef float    f32x4 __attribute__((ext_vector_type(4)));

#define WREC_E (K8N * NPAD * 8)    // 147456 f16 per term
#define WIN_E  (4 * NPAD * 8)      // 12288 f16 per term (K pad 32)

// Split fp32 weights into f16 hi/lo in MFMA B-fragment layout:
// idx = (k8*NPAD + n)*8 + (k&7), B[k][n] = W[n*K + k], zero-padded.
__global__ void prep_kernel(const float* __restrict__ W_rec,
                            const float* __restrict__ W_in,
                            const float* __restrict__ W_gate,
                            _Float16* __restrict__ Bh, _Float16* __restrict__ Bl,
                            _Float16* __restrict__ Wio)
{
    int idx = blockIdx.x * 256 + threadIdx.x;
    if (idx < WREC_E) {
        int k8 = idx / (NPAD * 8), rem = idx % (NPAD * 8);
        int n = rem >> 3, j = rem & 7, k = k8 * 8 + j;
        float v = (k < NET && n < NET) ? W_rec[n * NET + k] : 0.f;
        _Float16 h = (_Float16)v;
        Bh[idx] = h; Bl[idx] = (_Float16)(v - (float)h);
    } else if (idx < WREC_E + 2 * WIN_E) {
        // Wio layout: [0]=Wih, [1]=Wil, [2]=Wgh, [3]=Wgl, each WIN_E f16.
        int e = idx - WREC_E;                 // 0 .. 2*WIN_E-1
        int which = e / WIN_E;                // 0 = W_in, 1 = W_gate
        int f = e % WIN_E;
        int k8 = f / (NPAD * 8), rem = f % (NPAD * 8);
        int n = rem >> 3, j = rem & 7, k = k8 * 8 + j;
        const float* W = which ? W_gate : W_in;
        float v = (k < 28 && n < NET) ? W[n * 28 + k] : 0.f;
        _Float16 h = (_Float16)v;
        Wio[(2 * which) * WIN_E + f]     = h;
        Wio[(2 * which + 1) * WIN_E + f] = (_Float16)(v - (float)h);
    }
}

__device__ __forceinline__ float sigm(float v) { return 1.f / (1.f + __expf(-v)); }

__global__ __launch_bounds__(NTHR, 2)
void resonator_kernel(const float* __restrict__ x,
                      const int*   __restrict__ rsteps_p,
                      const float* __restrict__ b_in,
                      const float* __restrict__ b_gate,
                      const float* __restrict__ ln_g,
                      const float* __restrict__ ln_b,
                      const float* __restrict__ thr_p,
                      const float* __restrict__ intr_p,
                      const float* __restrict__ steep_p,
                      const float* __restrict__ reset_p,
                      const float* __restrict__ W_cls,
                      const float* __restrict__ b_cls,
                      const _Float16* __restrict__ Bh_g,
                      const _Float16* __restrict__ Bl_g,
                      const _Float16* __restrict__ Wio_g,
                      float* __restrict__ out)
{
    // Spikes in A-fragment layout, f16 hi/lo: idx = (k8*16 + m)*8 + (k&7)
    __shared__ __align__(16) _Float16 Ah[K8N * RPB * 8];       // 12 KB
    __shared__ __align__(16) _Float16 Al[K8N * RPB * 8];       // 12 KB
    __shared__ __align__(16) _Float16 xbuf[2][2][4 * RPB * 8]; // 4 KB [par][h/l]
    __shared__ __align__(16) _Float16 BcA[8 * 12 * 64 * 8];    // 96 KB: kt1-2 h+l
    __shared__ __align__(16) _Float16 BcB[8 * 3 * 64 * 8];     // 24 KB: kt3 h only
    __shared__ float red[8][33];                               // LN partials

    const int tid  = threadIdx.x;
    const int w    = tid >> 6;
    const int lane = tid & 63;
    const int quad = lane >> 4;
    const int l15  = lane & 15;
    const int row0 = blockIdx.x * RPB;

    // Per-column params for this thread's NTILE n-values (n = (w*3+i)*16 + l15)
    float gam[NTILE], bet[NTILE], thrv[NTILE], intv[NTILE], asp[NTILE], rscv[NTILE],
          binv[NTILE], bgtv[NTILE];
#pragma unroll
    for (int i = 0; i < NTILE; ++i) {
        int n_i = (w * NTILE + i) * 16 + l15;
        bool a = n_i < NET;
        gam[i]  = a ? ln_g[n_i]   : 0.f;
        bet[i]  = a ? ln_b[n_i]   : 0.f;
        thrv[i] = a ? thr_p[n_i]  : 0.f;
        intv[i] = a ? intr_p[n_i] : 0.f;
        asp[i]  = a ? fabsf(steep_p[n_i]) : 0.f;
        rscv[i] = a ? reset_p[n_i] : 0.f;
        binv[i] = a ? b_in[n_i]   : 0.f;
        bgtv[i] = a ? b_gate[n_i] : 0.f;
    }

    float pot[NTILE][4];
#pragma unroll
    for (int i = 0; i < NTILE; ++i)
#pragma unroll
        for (int r = 0; r < 4; ++r) pot[i][r] = 0.f;

    // Zero-init spike + x LDS (x pad cols stay 0 forever).
    for (int e = tid; e < K8N * RPB * 8; e += NTHR) { Ah[e] = (_Float16)0.f; Al[e] = (_Float16)0.f; }
    for (int e = tid; e < 2 * 2 * 4 * RPB * 8; e += NTHR) ((_Float16*)xbuf)[e] = (_Float16)0.f;

    const f16x8* Bph = (const f16x8*)Bh_g;
    const f16x8* Bpl = (const f16x8*)Bl_g;
    const f16x8* Aph = (const f16x8*)Ah;
    const f16x8* Apl = (const f16x8*)Al;
    const f16x8* Wp  = (const f16x8*)Wio_g;     // input weights: global (L2-hot)
    f16x8* BcAv = (f16x8*)BcA;
    f16x8* BcBv = (f16x8*)BcB;
    const int bb = quad * NPAD + w * (NTILE * 16) + l15;  // B-frag base (f16x8 units)

    // ---- Step-invariant B cache: kt0 in regs, kt1-2 + bh(kt3) in LDS ----
    f16x8 rbh[NTILE], rbl[NTILE];
#pragma unroll
    for (int i = 0; i < NTILE; ++i) {
        rbh[i] = Bph[bb + i * 16];
        rbl[i] = Bpl[bb + i * 16];
    }
#pragma unroll
    for (int kt = 1; kt < 3; ++kt)
#pragma unroll
        for (int i = 0; i < NTILE; ++i) {
            int op = (kt - 1) * 6 + i * 2;
            BcAv[(w * 12 + op) * 64 + lane]     = Bph[bb + i * 16 + kt * (4 * NPAD)];
            BcAv[(w * 12 + op + 1) * 64 + lane] = Bpl[bb + i * 16 + kt * (4 * NPAD)];
        }
#pragma unroll
    for (int i = 0; i < NTILE; ++i)
        BcBv[(w * 3 + i) * 64 + lane] = Bph[bb + i * 16 + 3 * (4 * NPAD)];

    // x staging: each thread owns one (m,f) element, fixed for all steps.
    const bool xact = tid < RPB * 28;
    const int  xm   = tid / 28;
    const int  xf   = tid - xm * 28;
    const int  xix  = ((xf >> 3) * RPB + xm) * 8 + (xf & 7);
    const float* xsrc = x + ((size_t)(row0 + xm) * 64) * 28 + xf;

    // Stage x for t=0 into parity-0 buffer.
    if (xact) {
        float v = xsrc[0];
        _Float16 h = (_Float16)v;
        xbuf[0][0][xix] = h; xbuf[0][1][xix] = (_Float16)(v - (float)h);
    }
    __syncthreads();

    // Gated-input lookahead: next_in[i][r] = input contribution for the
    // UPCOMING step, computed from x already staged in xbuf[par].
    float next_in[NTILE][4];
#define COMPUTE_NEXT_IN(PAR)                                                      \
    {                                                                             \
        const f16x8* Xh = (const f16x8*)xbuf[(PAR)][0];                           \
        const f16x8* Xl = (const f16x8*)xbuf[(PAR)][1];                           \
        f16x8 xa = Xh[lane];                                                      \
        f16x8 xb = Xl[lane];                                                      \
        _Pragma("unroll")                                                         \
        for (int i = 0; i < NTILE; ++i) {                                         \
            f16x8 ih = Wp[0 * (WIN_E / 8) + bb + i * 16];                         \
            f16x8 il = Wp[1 * (WIN_E / 8) + bb + i * 16];                         \
            f16x8 gh = Wp[2 * (WIN_E / 8) + bb + i * 16];                         \
            f16x8 gl = Wp[3 * (WIN_E / 8) + bb + i * 16];                         \
            f32x4 ia = (f32x4){binv[i], binv[i], binv[i], binv[i]};               \
            f32x4 ga = (f32x4){bgtv[i], bgtv[i], bgtv[i], bgtv[i]};               \
            ia = __builtin_amdgcn_mfma_f32_16x16x32_f16(xa, ih, ia, 0, 0, 0);     \
            ia = __builtin_amdgcn_mfma_f32_16x16x32_f16(xb, ih, ia, 0, 0, 0);     \
            ia = __builtin_amdgcn_mfma_f32_16x16x32_f16(xa, il, ia, 0, 0, 0);     \
            ga = __builtin_amdgcn_mfma_f32_16x16x32_f16(xa, gh, ga, 0, 0, 0);     \
            ga = __builtin_amdgcn_mfma_f32_16x16x32_f16(xb, gh, ga, 0, 0, 0);     \
            ga = __builtin_amdgcn_mfma_f32_16x16x32_f16(xa, gl, ga, 0, 0, 0);     \
            _Pragma("unroll")                                                     \
            for (int r = 0; r < 4; ++r) next_in[i][r] = ia[r] * sigm(ga[r]);      \
        }                                                                         \
    }
    COMPUTE_NEXT_IN(0)   // input for t=0

    const int Ttot = 64 + *rsteps_p;

    for (int t = 0; t < Ttot; ++t) {
        __syncthreads();   // barrier A: spikes/x/caches for step t visible

        f32x4 acc[NTILE];
#pragma unroll
        for (int i = 0; i < NTILE; ++i) acc[i] = (f32x4){0.f, 0.f, 0.f, 0.f};

        // ---- kt0 from register cache: zero-latency opening ----
        {
            f16x8 ah = Aph[lane];
            f16x8 al = Apl[lane];
#pragma unroll
            for (int i = 0; i < NTILE; ++i) {
                acc[i] = __builtin_amdgcn_mfma_f32_16x16x32_f16(ah, rbh[i], acc[i], 0, 0, 0);
                acc[i] = __builtin_amdgcn_mfma_f32_16x16x32_f16(al, rbh[i], acc[i], 0, 0, 0);
                acc[i] = __builtin_amdgcn_mfma_f32_16x16x32_f16(ah, rbl[i], acc[i], 0, 0, 0);
            }
        }
        // ---- kt1-2 from LDS cache ----
#pragma unroll
        for (int kt = 1; kt < 3; ++kt) {
            f16x8 ah = Aph[lane + kt * 64];
            f16x8 al = Apl[lane + kt * 64];
#pragma unroll
            for (int i = 0; i < NTILE; ++i) {
                f16x8 bh = BcAv[(w * 12 + (kt - 1) * 6 + i * 2) * 64 + lane];
                f16x8 bl = BcAv[(w * 12 + (kt - 1) * 6 + i * 2 + 1) * 64 + lane];
                acc[i] = __builtin_amdgcn_mfma_f32_16x16x32_f16(ah, bh, acc[i], 0, 0, 0);
                acc[i] = __builtin_amdgcn_mfma_f32_16x16x32_f16(al, bh, acc[i], 0, 0, 0);
                acc[i] = __builtin_amdgcn_mfma_f32_16x16x32_f16(ah, bl, acc[i], 0, 0, 0);
            }
        }
        // ---- kt3: bh from LDS, bl streamed ----
        {
            f16x8 ah = Aph[lane + 3 * 64];
            f16x8 al = Apl[lane + 3 * 64];
#pragma unroll
            for (int i = 0; i < NTILE; ++i) {
                f16x8 bh = BcBv[(w * 3 + i) * 64 + lane];
                f16x8 bl = Bpl[bb + i * 16 + 3 * (4 * NPAD)];
                acc[i] = __builtin_amdgcn_mfma_f32_16x16x32_f16(ah, bh, acc[i], 0, 0, 0);
                acc[i] = __builtin_amdgcn_mfma_f32_16x16x32_f16(al, bh, acc[i], 0, 0, 0);
                acc[i] = __builtin_amdgcn_mfma_f32_16x16x32_f16(ah, bl, acc[i], 0, 0, 0);
            }
        }
        // ---- kt4-11 streamed from L2 ----
#pragma unroll 4
        for (int q = 4; q < 12; ++q) {
            f16x8 ah = Aph[lane + q * 64];
            f16x8 al = Apl[lane + q * 64];
#pragma unroll
            for (int i = 0; i < NTILE; ++i) {
                f16x8 bh = Bph[bb + i * 16 + q * (4 * NPAD)];
                f16x8 bl = Bpl[bb + i * 16 + q * (4 * NPAD)];
                acc[i] = __builtin_amdgcn_mfma_f32_16x16x32_f16(ah, bh, acc[i], 0, 0, 0);
                acc[i] = __builtin_amdgcn_mfma_f32_16x16x32_f16(al, bh, acc[i], 0, 0, 0);
                acc[i] = __builtin_amdgcn_mfma_f32_16x16x32_f16(ah, bl, acc[i], 0, 0, 0);
            }
        }

        // ---- Add precomputed gated-input contribution (same FP position) ----
        if (t < 64) {
#pragma unroll
            for (int i = 0; i < NTILE; ++i)
#pragma unroll
                for (int r = 0; r < 4; ++r) acc[i][r] += next_in[i][r];
        }

        // ---- Stage x for t+1 into the other parity buffer ----
        if (t < 63 && xact) {
            float v = xsrc[(t + 1) * 28];
            _Float16 h = (_Float16)v;
            xbuf[(t + 1) & 1][0][xix] = h;
            xbuf[(t + 1) & 1][1][xix] = (_Float16)(v - (float)h);
        }

        // ---- LN stats stage 1: reduce over this wave's 48 columns ----
#pragma unroll
        for (int r = 0; r < 4; ++r) {
            float v  = acc[0][r] + acc[1][r] + acc[2][r];
            float v2 = acc[0][r] * acc[0][r] + acc[1][r] * acc[1][r] + acc[2][r] * acc[2][r];
#pragma unroll
            for (int off = 1; off < 16; off <<= 1) {
                v  += __shfl_xor(v,  off);
                v2 += __shfl_xor(v2, off);
            }
            if (l15 == 0) {
                red[w][(quad * 4 + r) * 2]     = v;
                red[w][(quad * 4 + r) * 2 + 1] = v2;
            }
        }

        __syncthreads();   // barrier B: red[] + x(t+1) visible

        // ---- LN finish, redundant per wave ----
        float mu_r[4], rs_r[4];
#pragma unroll
        for (int r = 0; r < 4; ++r) {
            int row2 = (quad * 4 + r) * 2;
            float val = red[l15 & 7][row2 + (l15 >> 3)];
            val += __shfl_xor(val, 1);
            val += __shfl_xor(val, 2);
            val += __shfl_xor(val, 4);
            float other = __shfl_xor(val, 8);
            float S  = (l15 < 8) ? val : other;    // sum of cur
            float S2 = (l15 < 8) ? other : val;    // sum of cur^2
            float mu = S * (1.f / NET);
            mu_r[r] = mu;
            rs_r[r] = rsqrtf(S2 * (1.f / NET) - mu * mu + 1e-5f);
        }

        // ---- LN apply + PulseTGAU neuron, write split spikes to A-layout ----
#pragma unroll
        for (int i = 0; i < NTILE; ++i) {
            int n_i  = (w * NTILE + i) * 16 + l15;
            int base = ((n_i >> 3) * RPB) * 8 + (n_i & 7);
#pragma unroll
            for (int r = 0; r < 4; ++r) {
                int m = quad * 4 + r;
                float cur = (acc[i][r] - mu_r[r]) * rs_r[r] * gam[i] + bet[i];
                float p   = pot[i][r] * 0.95f + cur + intv[i];
                float gp  = p - thrv[i];
                float sg  = sigm(gp * asp[i]);
                float sp  = sigm(gp);
                float o   = gp * sp * sg;
                pot[i][r] = p - rscv[i] * (gp * sg);
                _Float16 h = (_Float16)o;
                Ah[base + m * 8] = h;
                Al[base + m * 8] = (_Float16)(o - (float)h);
            }
        }

        // ---- Lookahead: input contribution for step t+1 (overlaps barrier) ----
        if (t < 63) COMPUTE_NEXT_IN((t + 1) & 1)
    }

    __syncthreads();
    // ---- Classifier epilogue ----
    if (tid < RPB * 10) {
        int r = tid / 10, c = tid - r * 10;
        const float* wc = W_cls + c * NET;
        float s = b_cls[c];
        for (int k = 0; k < NET; ++k) {
            int ix = ((k >> 3) * RPB + r) * 8 + (k & 7);
            float sv = (float)Ah[ix] + (float)Al[ix];
            s = fmaf(sv, wc[k], s);
        }
        out[(size_t)(row0 + r) * 10 + c] = s;
    }
}

extern "C" void kernel_launch(void* const* d_in, const int* in_sizes, int n_in,
                              void* d_out, int out_size, void* d_ws, size_t ws_size,
                              hipStream_t stream)
{
    const float* x      = (const float*)d_in[0];
    const int*   rsteps = (const int*)  d_in[1];
    const float* W_in   = (const float*)d_in[2];
    const float* b_in   = (const float*)d_in[3];
    const float* W_gate = (const float*)d_in[4];
    const float* b_gate = (const float*)d_in[5];
    const float* W_rec  = (const float*)d_in[6];
    const float* ln_g   = (const float*)d_in[7];
    const float* ln_b   = (const float*)d_in[8];
    const float* thr    = (const float*)d_in[9];
    const float* intr   = (const float*)d_in[10];
    const float* steep  = (const float*)d_in[11];
    const float* rsc    = (const float*)d_in[12];
    const float* W_cls  = (const float*)d_in[13];
    const float* b_cls  = (const float*)d_in[14];
    float*       out    = (float*)d_out;

    _Float16* Bh  = (_Float16*)d_ws;
    _Float16* Bl  = Bh + WREC_E;
    _Float16* Wio = Bl + WREC_E;     // 4*WIN_E: Wih, Wil, Wgh, Wgl

    const int total = WREC_E + 2 * WIN_E;
    prep_kernel<<<dim3((total + 255) / 256), dim3(256), 0, stream>>>(
        W_rec, W_in, W_gate, Bh, Bl, Wio);
    resonator_kernel<<<dim3(NBLK), dim3(NTHR), 0, stream>>>(
        x, rsteps, b_in, b_gate, ln_g, ln_b, thr, intr, steep, rsc,
        W_cls, b_cls, Bh, Bl, Wio, out);
}